// Round 1
// baseline (352.577 us; speedup 1.0000x reference)
//
#include <hip/hip_runtime.h>

// Problem constants (from reference setup_inputs)
#define DD 256        // D
#define DH 128        // D/2
#define TT 8          // T
#define SS 256        // S
#define BB 64         // B
#define NEDGE 500000  // E
#define MM 2048       // M
#define NEG_INF -10000000000.0f

// Kernel 0: v[d] = sum_j w1[d,j]*w2[j];  c = b1.w2 + b2
// Collapses the two linear layers into a single weight vector.
__global__ void precompute_vc(const float* __restrict__ w1,
                              const float* __restrict__ b1,
                              const float* __restrict__ w2,
                              const float* __restrict__ b2,
                              float* __restrict__ vc) {
    int d = threadIdx.x;  // 256 threads
    float acc = 0.f;
    #pragma unroll 4
    for (int j = 0; j < DH; ++j) acc += w1[d * DH + j] * w2[j];
    vc[d] = acc;
    if (d == 0) {
        float c = b2[0];
        for (int j = 0; j < DH; ++j) c += b1[j] * w2[j];
        vc[DD] = c;
    }
}

// Kernel 1: one wave (64 lanes) per edge.
// lemma[e] = sum_d types[scope,d]*types[goal,d]*v[d] + c
// types row i lives at tok + i*T*D (the t=0 slice), 1KB contiguous.
__global__ __launch_bounds__(256) void edge_kernel(
        const float* __restrict__ tok,
        const int* __restrict__ edges,
        const float* __restrict__ vc,
        float* __restrict__ out) {
    const int tid  = threadIdx.x;
    const int lane = tid & 63;
    const int wv   = tid >> 6;
    const int e    = blockIdx.x * 4 + wv;
    if (e >= NEDGE) return;

    const int scope = edges[e];
    const int goal  = edges[NEDGE + e];

    const float4* a  = (const float4*)(tok + (size_t)scope * (TT * DD));
    const float4* b  = (const float4*)(tok + (size_t)goal  * (TT * DD));
    const float4* v4 = (const float4*)vc;

    float4 av = a[lane];
    float4 bv = b[lane];
    float4 vv = v4[lane];

    float p = av.x * bv.x * vv.x + av.y * bv.y * vv.y +
              av.z * bv.z * vv.z + av.w * bv.w * vv.w;

    #pragma unroll
    for (int off = 32; off > 0; off >>= 1) p += __shfl_down(p, off);

    if (lane == 0) out[e] = p + vc[DD];
}

// Kernel 2: one block (4 waves) per m.
// lm_preds[m,s] = mask ? dot(mask_repr[m], types[bp[m], s]) : NEG_INF
// mask_repr row = tok + lm_idx[m]*D (contiguous 1KB).
// candidate row (bp,s) = tok + (bp*S + s)*T*D (contiguous 1KB).
__global__ __launch_bounds__(256) void lm_kernel(
        const float* __restrict__ tok,
        const int* __restrict__ lm_idx,
        const int* __restrict__ bp,
        const int* __restrict__ tpm,
        float* __restrict__ out) {
    const int m    = blockIdx.x;
    const int tid  = threadIdx.x;
    const int lane = tid & 63;
    const int wv   = tid >> 6;

    const int li = lm_idx[m];
    const int b  = bp[m];

    const float4* mrow = (const float4*)(tok + (size_t)li * DD);
    float4 mv = mrow[lane];  // each wave holds the full 256-float mask row

    const float* cbase = tok + (size_t)b * SS * TT * DD;

    #pragma unroll 4
    for (int i = 0; i < 64; ++i) {
        const int s = wv * 64 + i;
        const float4* crow = (const float4*)(cbase + (size_t)s * (TT * DD));
        float4 cv = crow[lane];
        float p = mv.x * cv.x + mv.y * cv.y + mv.z * cv.z + mv.w * cv.w;
        #pragma unroll
        for (int off = 32; off > 0; off >>= 1) p += __shfl_down(p, off);
        if (lane == 0) {
            float val = tpm[b * SS + s] ? p : NEG_INF;
            out[(size_t)m * SS + s] = val;
        }
    }
}

extern "C" void kernel_launch(void* const* d_in, const int* in_sizes, int n_in,
                              void* d_out, int out_size, void* d_ws, size_t ws_size,
                              hipStream_t stream) {
    const float* tok = (const float*)d_in[0];   // (B,S,T,D) fp32
    const float* w1  = (const float*)d_in[1];   // (D, D/2)
    const float* b1  = (const float*)d_in[2];   // (D/2,)
    const float* w2  = (const float*)d_in[3];   // (D/2, 1)
    const float* b2  = (const float*)d_in[4];   // (1,)
    const int* edges = (const int*)d_in[5];     // (2, E)
    const int* lmi   = (const int*)d_in[6];     // (M,)
    const int* bp    = (const int*)d_in[7];     // (M,)
    const int* tpm   = (const int*)d_in[8];     // (B, S) bool->int

    float* out_lemmas = (float*)d_out;                 // E floats
    float* out_lm     = (float*)d_out + NEDGE;         // M*S floats
    float* vc         = (float*)d_ws;                  // 257 floats

    precompute_vc<<<1, 256, 0, stream>>>(w1, b1, w2, b2, vc);
    edge_kernel<<<(NEDGE + 3) / 4, 256, 0, stream>>>(tok, edges, vc, out_lemmas);
    lm_kernel<<<MM, 256, 0, stream>>>(tok, lmi, bp, tpm, out_lm);
}

// Round 2
// 352.179 us; speedup vs baseline: 1.0011x; 1.0011x over previous
//
#include <hip/hip_runtime.h>

#define DD 256        // D
#define SS 256        // S
#define BB 64         // B
#define NEDGE 500000  // E
#define MM 2048       // M
#define NEG_INF -10000000000.0f
#define ROWF4 512     // (T*D)/4 : float4 stride between consecutive (b,s) type rows
#define SEGF4 8       // float4 per 32-float segment

__device__ __forceinline__ float bflo(unsigned u) { return __uint_as_float(u << 16); }
__device__ __forceinline__ float bfhi(unsigned u) { return __uint_as_float(u & 0xFFFF0000u); }

// Kernel 0: v[d] = sum_j w1[d,j]*w2[j];  vc[256] = b1.w2 + b2
__global__ void precompute_vc(const float* __restrict__ w1,
                              const float* __restrict__ b1,
                              const float* __restrict__ w2,
                              const float* __restrict__ b2,
                              float* __restrict__ vc) {
    int d = threadIdx.x;  // 256 threads
    float acc = 0.f;
    #pragma unroll 4
    for (int j = 0; j < DD / 2; ++j) acc += w1[d * (DD / 2) + j] * w2[j];
    vc[d] = acc;
    if (d == 0) {
        float c = b2[0];
        for (int j = 0; j < DD / 2; ++j) c += b1[j] * w2[j];
        vc[DD] = c;
    }
}

// Kernel 1: counting-sort m indices by batch pointer (single block).
__global__ void sort_m(const int* __restrict__ bp,
                       int* __restrict__ msorted,
                       int* __restrict__ bstart) {
    __shared__ int hist[BB];
    __shared__ int offs[BB + 1];
    const int t = threadIdx.x;  // 256
    if (t < BB) hist[t] = 0;
    __syncthreads();
    for (int m = t; m < MM; m += 256) atomicAdd(&hist[bp[m]], 1);
    __syncthreads();
    if (t == 0) {
        int acc = 0;
        for (int i = 0; i < BB; ++i) { offs[i] = acc; acc += hist[i]; }
        offs[BB] = acc;
    }
    __syncthreads();
    if (t < BB + 1) bstart[t] = offs[t];
    __syncthreads();
    for (int m = t; m < MM; m += 256) {
        int pos = atomicAdd(&offs[bp[m]], 1);
        msorted[pos] = m;
    }
}

// Kernel 2 (x8 passes): segmented edge dot.
// Pass k gathers only the 128B slice d in [32k, 32k+32) of each row -> 2MB hot
// set, L2-resident. 8 lanes per edge, 3-step shuffle reduce, RMW accumulate.
__global__ __launch_bounds__(256) void edge_seg(
        const float* __restrict__ tok,
        const int* __restrict__ edges,
        const float* __restrict__ vc,
        float* __restrict__ out, int k) {
    const int g   = blockIdx.x * 32 + (threadIdx.x >> 3);  // edge id (grid exact)
    const int sub = threadIdx.x & 7;

    const int scope = __builtin_nontemporal_load(edges + g);
    const int goal  = __builtin_nontemporal_load(edges + NEDGE + g);

    const float4* t4 = (const float4*)tok;
    const float4 a = t4[(size_t)scope * ROWF4 + k * SEGF4 + sub];
    const float4 b = t4[(size_t)goal  * ROWF4 + k * SEGF4 + sub];
    const float4 v = ((const float4*)vc)[k * SEGF4 + sub];

    float p = a.x * b.x * v.x + a.y * b.y * v.y +
              a.z * b.z * v.z + a.w * b.w * v.w;
    p += __shfl_down(p, 4, 8);
    p += __shfl_down(p, 2, 8);
    p += __shfl_down(p, 1, 8);

    if (sub == 0) {
        if (k == 0) {
            __builtin_nontemporal_store(p + vc[DD], out + g);
        } else {
            float prev = __builtin_nontemporal_load(out + g);
            __builtin_nontemporal_store(prev + p, out + g);
        }
    }
}

// Kernel 3: per-batch grouped lm_preds GEMM.
// Block (b, s-tile of 64, chunk of <=32 masks). Masks + candidate rows staged
// in LDS as truncated bf16 (lm threshold ~2e8; bf16 error ~0.3 irrelevant).
// 2x2 register tile per thread; stride 132 uints (33 uint4, odd) -> conflict-free.
__global__ __launch_bounds__(256) void lm_gemm(
        const float* __restrict__ tok,
        const int* __restrict__ lmi,
        const int* __restrict__ msorted,
        const int* __restrict__ bstart,
        const int* __restrict__ tpm,
        float* __restrict__ out) {
    const int b  = blockIdx.x;
    const int st = blockIdx.y;  // s-tile of 64
    const int ch = blockIdx.z;

    const int s0 = bstart[b], s1 = bstart[b + 1];
    const int base = s0 + ch * 32;
    if (base >= s1) return;
    const int nm = min(32, s1 - base);

    const int t = threadIdx.x;
    __shared__ unsigned lmaskU[32 * 132];
    __shared__ unsigned srowU[32 * 132];
    __shared__ int mids[32];

    if (t < 32) mids[t] = msorted[base + min(t, nm - 1)];
    __syncthreads();

    // stage mask rows (from full token space via lm_indices)
    for (int f = t; f < nm * 64; f += 256) {
        const int i = f >> 6, q = f & 63;
        const float4 src = ((const float4*)(tok + (size_t)lmi[mids[i]] * DD))[q];
        unsigned u0 = (__float_as_uint(src.y) & 0xFFFF0000u) | (__float_as_uint(src.x) >> 16);
        unsigned u1 = (__float_as_uint(src.w) & 0xFFFF0000u) | (__float_as_uint(src.z) >> 16);
        *(uint2*)&lmaskU[i * 132 + q * 2] = make_uint2(u0, u1);
    }

    const int i2 = t & 15;
    const int sg = t >> 4;  // [0,16)

    for (int sub = 0; sub < 2; ++sub) {
        const int sbase = st * 64 + sub * 32;
        __syncthreads();  // protects srow reuse + orders mask staging before compute
        for (int f = t; f < 32 * 64; f += 256) {
            const int r = f >> 6, q = f & 63;
            const size_t row = (size_t)b * SS + sbase + r;
            const float4 src = ((const float4*)tok)[row * ROWF4 + q];
            unsigned u0 = (__float_as_uint(src.y) & 0xFFFF0000u) | (__float_as_uint(src.x) >> 16);
            unsigned u1 = (__float_as_uint(src.w) & 0xFFFF0000u) | (__float_as_uint(src.z) >> 16);
            *(uint2*)&srowU[r * 132 + q * 2] = make_uint2(u0, u1);
        }
        __syncthreads();

        float a00 = 0.f, a01 = 0.f, a10 = 0.f, a11 = 0.f;
        #pragma unroll 4
        for (int stp = 0; stp < 32; ++stp) {
            const uint4 A0 = *(const uint4*)&lmaskU[i2 * 132 + stp * 4];
            const uint4 A1 = *(const uint4*)&lmaskU[(i2 + 16) * 132 + stp * 4];
            const uint4 B0 = *(const uint4*)&srowU[sg * 132 + stp * 4];
            const uint4 B1 = *(const uint4*)&srowU[(sg + 16) * 132 + stp * 4];
            float a0[8], a1[8], b0[8], b1[8];
            a0[0] = bflo(A0.x); a0[1] = bfhi(A0.x); a0[2] = bflo(A0.y); a0[3] = bfhi(A0.y);
            a0[4] = bflo(A0.z); a0[5] = bfhi(A0.z); a0[6] = bflo(A0.w); a0[7] = bfhi(A0.w);
            a1[0] = bflo(A1.x); a1[1] = bfhi(A1.x); a1[2] = bflo(A1.y); a1[3] = bfhi(A1.y);
            a1[4] = bflo(A1.z); a1[5] = bfhi(A1.z); a1[6] = bflo(A1.w); a1[7] = bfhi(A1.w);
            b0[0] = bflo(B0.x); b0[1] = bfhi(B0.x); b0[2] = bflo(B0.y); b0[3] = bfhi(B0.y);
            b0[4] = bflo(B0.z); b0[5] = bfhi(B0.z); b0[6] = bflo(B0.w); b0[7] = bfhi(B0.w);
            b1[0] = bflo(B1.x); b1[1] = bfhi(B1.x); b1[2] = bflo(B1.y); b1[3] = bfhi(B1.y);
            b1[4] = bflo(B1.z); b1[5] = bfhi(B1.z); b1[6] = bflo(B1.w); b1[7] = bfhi(B1.w);
            #pragma unroll
            for (int j = 0; j < 8; ++j) {
                a00 = fmaf(a0[j], b0[j], a00);
                a01 = fmaf(a0[j], b1[j], a01);
                a10 = fmaf(a1[j], b0[j], a10);
                a11 = fmaf(a1[j], b1[j], a11);
            }
        }

        const int sA = sbase + sg, sB = sA + 16;
        const bool mA = tpm[b * SS + sA] != 0;
        const bool mB = tpm[b * SS + sB] != 0;
        if (i2 < nm) {
            const int m0 = mids[i2];
            out[(size_t)m0 * SS + sA] = mA ? a00 : NEG_INF;
            out[(size_t)m0 * SS + sB] = mB ? a01 : NEG_INF;
        }
        if (i2 + 16 < nm) {
            const int m1 = mids[i2 + 16];
            out[(size_t)m1 * SS + sA] = mA ? a10 : NEG_INF;
            out[(size_t)m1 * SS + sB] = mB ? a11 : NEG_INF;
        }
    }
}

extern "C" void kernel_launch(void* const* d_in, const int* in_sizes, int n_in,
                              void* d_out, int out_size, void* d_ws, size_t ws_size,
                              hipStream_t stream) {
    const float* tok = (const float*)d_in[0];
    const float* w1  = (const float*)d_in[1];
    const float* b1  = (const float*)d_in[2];
    const float* w2  = (const float*)d_in[3];
    const float* b2  = (const float*)d_in[4];
    const int* edges = (const int*)d_in[5];
    const int* lmi   = (const int*)d_in[6];
    const int* bp    = (const int*)d_in[7];
    const int* tpm   = (const int*)d_in[8];

    float* out_lemmas = (float*)d_out;
    float* out_lm     = (float*)d_out + NEDGE;

    float* vc    = (float*)d_ws;                       // 257 floats
    int* msorted = (int*)((char*)d_ws + 2048);         // 2048 ints
    int* bstart  = msorted + MM;                       // 65 ints

    precompute_vc<<<1, 256, 0, stream>>>(w1, b1, w2, b2, vc);
    sort_m<<<1, 256, 0, stream>>>(bp, msorted, bstart);
    for (int k = 0; k < 8; ++k)
        edge_seg<<<NEDGE / 32, 256, 0, stream>>>(tok, edges, vc, out_lemmas, k);
    lm_gemm<<<dim3(BB, 4, 8), 256, 0, stream>>>(tok, lmi, msorted, bstart, tpm, out_lm);
}

// Round 3
// 350.769 us; speedup vs baseline: 1.0052x; 1.0040x over previous
//
#include <hip/hip_runtime.h>

#define DD 256        // D
#define SS 256        // S
#define BB 64         // B
#define NEDGE 500000  // E
#define MM 2048       // M
#define NEG_INF -10000000000.0f
#define ROWF4 512     // float4 stride between consecutive (b,s) type rows in token_reprs
#define NROWS (BB * SS)  // 16384

// workspace byte offsets
#define OFF_VC     0
#define OFF_MSORT  4096
#define OFF_BSTART (4096 + MM * 4)
#define OFF_PSLAB  (1 << 16)
#define OFF_QSLAB  ((1 << 16) + (8 << 20))
#define OFF_P2     ((1 << 16) + (16 << 20))

__device__ __forceinline__ float bflo(unsigned u) { return __uint_as_float(u << 16); }
__device__ __forceinline__ float bfhi(unsigned u) { return __uint_as_float(u & 0xFFFF0000u); }
__device__ __forceinline__ unsigned short bf_rne(float f) {
    unsigned u = __float_as_uint(f);
    return (unsigned short)((u + 0x7FFFu + ((u >> 16) & 1u)) >> 16);
}
__device__ __forceinline__ unsigned pack2_rne(float a, float b) {
    return (unsigned)bf_rne(a) | ((unsigned)bf_rne(b) << 16);
}

// v[d] = sum_j w1[d,j]*w2[j];  vc[256] = b1.w2 + b2
__global__ void precompute_vc(const float* __restrict__ w1,
                              const float* __restrict__ b1,
                              const float* __restrict__ w2,
                              const float* __restrict__ b2,
                              float* __restrict__ vc) {
    int d = threadIdx.x;
    float acc = 0.f;
    #pragma unroll 4
    for (int j = 0; j < DD / 2; ++j) acc += w1[d * (DD / 2) + j] * w2[j];
    vc[d] = acc;
    if (d == 0) {
        float c = b2[0];
        for (int j = 0; j < DD / 2; ++j) c += b1[j] * w2[j];
        vc[DD] = c;
    }
}

// counting-sort m by batch pointer
__global__ void sort_m(const int* __restrict__ bp,
                       int* __restrict__ msorted,
                       int* __restrict__ bstart) {
    __shared__ int hist[BB];
    __shared__ int offs[BB + 1];
    const int t = threadIdx.x;
    if (t < BB) hist[t] = 0;
    __syncthreads();
    for (int m = t; m < MM; m += 256) atomicAdd(&hist[bp[m]], 1);
    __syncthreads();
    if (t == 0) {
        int acc = 0;
        for (int i = 0; i < BB; ++i) { offs[i] = acc; acc += hist[i]; }
        offs[BB] = acc;
    }
    __syncthreads();
    if (t < BB + 1) bstart[t] = offs[t];
    __syncthreads();
    for (int m = t; m < MM; m += 256) {
        int pos = atomicAdd(&offs[bp[m]], 1);
        msorted[pos] = m;
    }
}

// Compact the strided t=0 type rows into DENSE bf16 tables:
//  Pslab[k][row][32] = A slice, Qslab[k][row][32] = (A*v) slice  (edge passes)
//  P2[row][256]                                                  (lm staging)
// Dense layout -> consecutive rows hit consecutive L2 sets (no aliasing).
__global__ __launch_bounds__(256) void compact(
        const float* __restrict__ tok, const float* __restrict__ vc,
        unsigned* __restrict__ pslab, unsigned* __restrict__ qslab,
        unsigned* __restrict__ p2) {
    const int lane = threadIdx.x & 63;
    const int row  = blockIdx.x * 4 + (threadIdx.x >> 6);  // one wave per row
    const float4 a = ((const float4*)tok)[(size_t)row * ROWF4 + lane];
    const float4 v = ((const float4*)vc)[lane];
    unsigned p0 = pack2_rne(a.x, a.y), p1 = pack2_rne(a.z, a.w);
    unsigned q0 = pack2_rne(a.x * v.x, a.y * v.y), q1 = pack2_rne(a.z * v.z, a.w * v.w);
    const int k = lane >> 3, sub = lane & 7;
    const size_t si = ((size_t)(k * NROWS + row) * 8 + sub) * 2;
    pslab[si] = p0; pslab[si + 1] = p1;
    qslab[si] = q0; qslab[si + 1] = q1;
    const size_t pi = (size_t)row * 128 + lane * 2;
    p2[pi] = p0; p2[pi + 1] = p1;
}

// Pass k: lemma[e] += dot(Pslab[k][scope], Qslab[k][goal]).  Hot set = 2 MB
// dense -> L2-resident. 8 lanes/edge, 64 B per table per edge.
__global__ __launch_bounds__(256) void edge_seg(
        const unsigned* __restrict__ pslab, const unsigned* __restrict__ qslab,
        const int* __restrict__ edges, const float* __restrict__ vc,
        float* __restrict__ out, int k) {
    const int g   = blockIdx.x * 32 + (threadIdx.x >> 3);
    const int sub = threadIdx.x & 7;
    const int scope = __builtin_nontemporal_load(edges + g);
    const int goal  = __builtin_nontemporal_load(edges + NEDGE + g);
    const uint2 pu = *(const uint2*)(pslab + ((size_t)(k * NROWS + scope) * 8 + sub) * 2);
    const uint2 qu = *(const uint2*)(qslab + ((size_t)(k * NROWS + goal ) * 8 + sub) * 2);
    float p = bflo(pu.x) * bflo(qu.x) + bfhi(pu.x) * bfhi(qu.x)
            + bflo(pu.y) * bflo(qu.y) + bfhi(pu.y) * bfhi(qu.y);
    p += __shfl_down(p, 4, 8);
    p += __shfl_down(p, 2, 8);
    p += __shfl_down(p, 1, 8);
    if (sub == 0) {
        if (k == 0) {
            __builtin_nontemporal_store(p + vc[DD], out + g);
        } else {
            float prev = __builtin_nontemporal_load(out + g);
            __builtin_nontemporal_store(prev + p, out + g);
        }
    }
}

// Per-batch grouped lm GEMM with masked-column skip.
__global__ __launch_bounds__(256) void lm_gemm(
        const float* __restrict__ tok,
        const unsigned* __restrict__ p2,
        const int* __restrict__ lmi,
        const int* __restrict__ msorted,
        const int* __restrict__ bstart,
        const int* __restrict__ tpm,
        float* __restrict__ out) {
    const int b  = blockIdx.x;
    const int st = blockIdx.y;   // 64-wide s tile
    const int ch = blockIdx.z;   // mask chunk
    const int s0 = bstart[b], s1 = bstart[b + 1];
    const int base = s0 + ch * 32;
    if (base >= s1) return;
    const int nm = min(32, s1 - base);
    const int t = threadIdx.x;

    __shared__ unsigned lmaskU[32 * 132];
    __shared__ unsigned srowU[32 * 132];
    __shared__ int mids[32];
    __shared__ int sact[64];
    __shared__ int snact;

    if (t < 32) mids[t] = msorted[base + min(t, nm - 1)];
    if (t >= 64 && t < 128) {  // wave 1: ballot-compact active columns
        int lt = t - 64;
        bool act = tpm[b * SS + st * 64 + lt] != 0;
        unsigned long long mk = __ballot(act);
        if (act) sact[__popcll(mk & ((1ull << lt) - 1))] = lt;
        if (lt == 0) snact = (int)__popcll(mk);
    }
    __syncthreads();

    // stage mask rows (truncate to bf16; lm threshold is huge)
    for (int f = t; f < nm * 64; f += 256) {
        int i = f >> 6, q = f & 63;
        const float4 src = ((const float4*)(tok + (size_t)lmi[mids[i]] * DD))[q];
        unsigned u0 = (__float_as_uint(src.y) & 0xFFFF0000u) | (__float_as_uint(src.x) >> 16);
        unsigned u1 = (__float_as_uint(src.w) & 0xFFFF0000u) | (__float_as_uint(src.z) >> 16);
        *(uint2*)&lmaskU[i * 132 + q * 2] = make_uint2(u0, u1);
    }
    // NEG_INF for inactive columns
    for (int f = t; f < nm * 64; f += 256) {
        int i = f >> 6, c = f & 63;
        if (!tpm[b * SS + st * 64 + c])
            out[(size_t)mids[i] * SS + st * 64 + c] = NEG_INF;
    }
    __syncthreads();

    const int nact = snact;
    const int i2 = t & 15, sg = t >> 4;

    for (int g = 0; g * 32 < nact; ++g) {
        if (g) __syncthreads();
        const int nv = min(32, nact - g * 32);
        for (int f = t; f < nv * 32; f += 256) {
            int r = f >> 5, q = f & 31;
            size_t row = (size_t)b * SS + st * 64 + sact[g * 32 + r];
            *(uint4*)&srowU[r * 132 + q * 4] = ((const uint4*)p2)[row * 32 + q];
        }
        __syncthreads();

        float a00 = 0.f, a01 = 0.f, a10 = 0.f, a11 = 0.f;
        #pragma unroll 4
        for (int stp = 0; stp < 32; ++stp) {
            const uint4 A0 = *(const uint4*)&lmaskU[i2 * 132 + stp * 4];
            const uint4 A1 = *(const uint4*)&lmaskU[(i2 + 16) * 132 + stp * 4];
            const uint4 B0 = *(const uint4*)&srowU[sg * 132 + stp * 4];
            const uint4 B1 = *(const uint4*)&srowU[(sg + 16) * 132 + stp * 4];
            float a0[8], a1[8], b0[8], b1[8];
            a0[0] = bflo(A0.x); a0[1] = bfhi(A0.x); a0[2] = bflo(A0.y); a0[3] = bfhi(A0.y);
            a0[4] = bflo(A0.z); a0[5] = bfhi(A0.z); a0[6] = bflo(A0.w); a0[7] = bfhi(A0.w);
            a1[0] = bflo(A1.x); a1[1] = bfhi(A1.x); a1[2] = bflo(A1.y); a1[3] = bfhi(A1.y);
            a1[4] = bflo(A1.z); a1[5] = bfhi(A1.z); a1[6] = bflo(A1.w); a1[7] = bfhi(A1.w);
            b0[0] = bflo(B0.x); b0[1] = bfhi(B0.x); b0[2] = bflo(B0.y); b0[3] = bfhi(B0.y);
            b0[4] = bflo(B0.z); b0[5] = bfhi(B0.z); b0[6] = bflo(B0.w); b0[7] = bfhi(B0.w);
            b1[0] = bflo(B1.x); b1[1] = bfhi(B1.x); b1[2] = bflo(B1.y); b1[3] = bfhi(B1.y);
            b1[4] = bflo(B1.z); b1[5] = bfhi(B1.z); b1[6] = bflo(B1.w); b1[7] = bfhi(B1.w);
            #pragma unroll
            for (int j = 0; j < 8; ++j) {
                a00 = fmaf(a0[j], b0[j], a00);
                a01 = fmaf(a0[j], b1[j], a01);
                a10 = fmaf(a1[j], b0[j], a10);
                a11 = fmaf(a1[j], b1[j], a11);
            }
        }

        const int iA = g * 32 + sg, iB = iA + 16;
        if (i2 < nm) {
            size_t ob = (size_t)mids[i2] * SS + st * 64;
            if (iA < nact) out[ob + sact[iA]] = a00;
            if (iB < nact) out[ob + sact[iB]] = a01;
        }
        if (i2 + 16 < nm) {
            size_t ob = (size_t)mids[i2 + 16] * SS + st * 64;
            if (iA < nact) out[ob + sact[iA]] = a10;
            if (iB < nact) out[ob + sact[iB]] = a11;
        }
    }
}

extern "C" void kernel_launch(void* const* d_in, const int* in_sizes, int n_in,
                              void* d_out, int out_size, void* d_ws, size_t ws_size,
                              hipStream_t stream) {
    const float* tok = (const float*)d_in[0];
    const float* w1  = (const float*)d_in[1];
    const float* b1  = (const float*)d_in[2];
    const float* w2  = (const float*)d_in[3];
    const float* b2  = (const float*)d_in[4];
    const int* edges = (const int*)d_in[5];
    const int* lmi   = (const int*)d_in[6];
    const int* bp    = (const int*)d_in[7];
    const int* tpm   = (const int*)d_in[8];

    float* out_lemmas = (float*)d_out;
    float* out_lm     = (float*)d_out + NEDGE;

    char* ws = (char*)d_ws;
    float* vc        = (float*)(ws + OFF_VC);
    int* msorted     = (int*)(ws + OFF_MSORT);
    int* bstart      = (int*)(ws + OFF_BSTART);
    unsigned* pslab  = (unsigned*)(ws + OFF_PSLAB);
    unsigned* qslab  = (unsigned*)(ws + OFF_QSLAB);
    unsigned* p2     = (unsigned*)(ws + OFF_P2);

    precompute_vc<<<1, 256, 0, stream>>>(w1, b1, w2, b2, vc);
    sort_m<<<1, 256, 0, stream>>>(bp, msorted, bstart);
    compact<<<NROWS / 4, 256, 0, stream>>>(tok, vc, pslab, qslab, p2);
    for (int k = 0; k < 8; ++k)
        edge_seg<<<NEDGE / 32, 256, 0, stream>>>(pslab, qslab, edges, vc, out_lemmas, k);
    lm_gemm<<<dim3(BB, 4, 8), 256, 0, stream>>>(tok, p2, lmi, msorted, bstart, tpm, out_lm);
}

// Round 4
// 290.363 us; speedup vs baseline: 1.2143x; 1.2080x over previous
//
#include <hip/hip_runtime.h>

#define DD 256        // D
#define SS 256        // S
#define BB 64         // B
#define NEDGE 500000  // E
#define MM 2048       // M
#define NEG_INF -10000000000.0f
#define ROWF4 512     // float4 stride between consecutive (b,s) type rows in token_reprs
#define NROWS (BB * SS)  // 16384

// workspace byte offsets
#define OFF_VC     0
#define OFF_MSORT  4096
#define OFF_BSTART (4096 + MM * 4)
#define OFF_PSLAB  (1 << 16)
#define OFF_QSLAB  ((1 << 16) + (8 << 20))
#define OFF_P2     ((1 << 16) + (16 << 20))
#define OFF_MROWS  ((1 << 16) + (24 << 20))

__device__ __forceinline__ float bflo(unsigned u) { return __uint_as_float(u << 16); }
__device__ __forceinline__ float bfhi(unsigned u) { return __uint_as_float(u & 0xFFFF0000u); }
__device__ __forceinline__ unsigned short bf_rne(float f) {
    unsigned u = __float_as_uint(f);
    return (unsigned short)((u + 0x7FFFu + ((u >> 16) & 1u)) >> 16);
}
__device__ __forceinline__ unsigned pack2_rne(float a, float b) {
    return (unsigned)bf_rne(a) | ((unsigned)bf_rne(b) << 16);
}

// block 0: vc[d] = sum_j w1[d,j]*w2[j], vc[256] = b1.w2+b2
// block 1: counting-sort m by batch pointer
__global__ void setup_k(const float* __restrict__ w1, const float* __restrict__ b1,
                        const float* __restrict__ w2, const float* __restrict__ b2,
                        const int* __restrict__ bp,
                        float* __restrict__ vc, int* __restrict__ msorted,
                        int* __restrict__ bstart) {
    const int t = threadIdx.x;
    if (blockIdx.x == 0) {
        float acc = 0.f;
        #pragma unroll 4
        for (int j = 0; j < DD / 2; ++j) acc += w1[t * (DD / 2) + j] * w2[j];
        vc[t] = acc;
        if (t == 0) {
            float c = b2[0];
            for (int j = 0; j < DD / 2; ++j) c += b1[j] * w2[j];
            vc[DD] = c;
        }
    } else {
        __shared__ int hist[BB];
        __shared__ int offs[BB + 1];
        if (t < BB) hist[t] = 0;
        __syncthreads();
        for (int m = t; m < MM; m += 256) atomicAdd(&hist[bp[m]], 1);
        __syncthreads();
        if (t == 0) {
            int acc = 0;
            for (int i = 0; i < BB; ++i) { offs[i] = acc; acc += hist[i]; }
            offs[BB] = acc;
        }
        __syncthreads();
        if (t < BB + 1) bstart[t] = offs[t];
        __syncthreads();
        for (int m = t; m < MM; m += 256) {
            int pos = atomicAdd(&offs[bp[m]], 1);
            msorted[pos] = m;
        }
    }
}

// Compact strided fp32 rows into dense bf16 tables:
//  blocks [0, NROWS/4): type rows -> Pslab/Qslab (slice-major) + P2 (row-major)
//  blocks [NROWS/4, +MM/4): mask rows via lm_indices -> mrows (row-major)
__global__ __launch_bounds__(256) void compact(
        const float* __restrict__ tok, const float* __restrict__ vc,
        const int* __restrict__ lmi,
        unsigned* __restrict__ pslab, unsigned* __restrict__ qslab,
        unsigned* __restrict__ p2, unsigned* __restrict__ mrows) {
    const int lane = threadIdx.x & 63;
    const int w    = threadIdx.x >> 6;
    if (blockIdx.x < NROWS / 4) {
        const int row = blockIdx.x * 4 + w;
        const float4 a = ((const float4*)tok)[(size_t)row * ROWF4 + lane];
        const float4 v = ((const float4*)vc)[lane];
        unsigned p0 = pack2_rne(a.x, a.y), p1 = pack2_rne(a.z, a.w);
        unsigned q0 = pack2_rne(a.x * v.x, a.y * v.y), q1 = pack2_rne(a.z * v.z, a.w * v.w);
        const int k = lane >> 3, sub = lane & 7;
        const size_t si = (size_t)(k * NROWS + row) * 16 + sub * 2;
        pslab[si] = p0; pslab[si + 1] = p1;
        qslab[si] = q0; qslab[si + 1] = q1;
        const size_t pi = (size_t)row * 128 + lane * 2;
        p2[pi] = p0; p2[pi + 1] = p1;
    } else {
        const int m = (blockIdx.x - NROWS / 4) * 4 + w;
        const float4 a = ((const float4*)(tok + (size_t)lmi[m] * DD))[lane];
        mrows[(size_t)m * 128 + lane * 2]     = pack2_rne(a.x, a.y);
        mrows[(size_t)m * 128 + lane * 2 + 1] = pack2_rne(a.z, a.w);
    }
}

// Fused edge kernel: 256 edges/block, k-loop (8 slices of 32 dims) inside.
// Indices in LDS once; acc[8] in registers; all resident blocks sweep k in
// the same order -> instantaneous hot slab ~2-4MB, L2-resident.
__global__ __launch_bounds__(256) void edge_fused(
        const unsigned* __restrict__ pslab, const unsigned* __restrict__ qslab,
        const int* __restrict__ edges, const float* __restrict__ vc,
        float* __restrict__ out) {
    const int t = threadIdx.x;
    const int lane = t & 63, w = t >> 6;
    const int sub = lane & 7, j = lane >> 3;
    const int e0 = blockIdx.x * 256;
    __shared__ int sIdx[2][256];
    __shared__ float accs[256];
    const int e = e0 + t;
    const bool val = e < NEDGE;
    sIdx[0][t] = val ? __builtin_nontemporal_load(edges + e) : 0;
    sIdx[1][t] = val ? __builtin_nontemporal_load(edges + NEDGE + e) : 0;
    __syncthreads();

    float acc[8];
    #pragma unroll
    for (int i = 0; i < 8; ++i) acc[i] = 0.f;
    const int slotbase = w * 64 + j;  // + i*8

    #pragma unroll 1
    for (int k = 0; k < 8; ++k) {
        const size_t kb = (size_t)k * NROWS;
        #pragma unroll
        for (int i = 0; i < 8; ++i) {
            const int slot = slotbase + i * 8;
            const int sc = sIdx[0][slot];
            const int gl = sIdx[1][slot];
            const uint2 pu = *(const uint2*)(pslab + (kb + sc) * 16 + sub * 2);
            const uint2 qu = *(const uint2*)(qslab + (kb + gl) * 16 + sub * 2);
            acc[i] += bflo(pu.x) * bflo(qu.x) + bfhi(pu.x) * bfhi(qu.x)
                    + bflo(pu.y) * bflo(qu.y) + bfhi(pu.y) * bfhi(qu.y);
        }
    }
    #pragma unroll
    for (int i = 0; i < 8; ++i) {
        float p = acc[i];
        p += __shfl_down(p, 4, 8);
        p += __shfl_down(p, 2, 8);
        p += __shfl_down(p, 1, 8);
        if (sub == 0) accs[slotbase + i * 8] = p;
    }
    __syncthreads();
    if (val) __builtin_nontemporal_store(accs[t] + vc[DD], out + e);
}

// Per-batch grouped lm GEMM with masked-column skip; A and B both staged from
// dense bf16 tables.
__global__ __launch_bounds__(256) void lm_gemm(
        const unsigned* __restrict__ p2,
        const unsigned* __restrict__ mrows,
        const int* __restrict__ msorted,
        const int* __restrict__ bstart,
        const int* __restrict__ tpm,
        float* __restrict__ out) {
    const int b  = blockIdx.x;
    const int st = blockIdx.y;   // 64-wide s tile
    const int ch = blockIdx.z;   // mask chunk
    const int s0 = bstart[b], s1 = bstart[b + 1];
    const int base = s0 + ch * 32;
    if (base >= s1) return;
    const int nm = min(32, s1 - base);
    const int t = threadIdx.x;

    __shared__ unsigned lmaskU[32 * 132];
    __shared__ unsigned srowU[32 * 132];
    __shared__ int mids[32];
    __shared__ int sact[64];
    __shared__ int snact;

    if (t < 32) mids[t] = msorted[base + min(t, nm - 1)];
    if (t >= 64 && t < 128) {  // wave 1: ballot-compact active columns
        int lt = t - 64;
        bool act = tpm[b * SS + st * 64 + lt] != 0;
        unsigned long long mk = __ballot(act);
        if (act) sact[__popcll(mk & ((1ull << lt) - 1))] = lt;
        if (lt == 0) snact = (int)__popcll(mk);
    }
    __syncthreads();

    for (int f = t; f < nm * 32; f += 256) {
        int r = f >> 5, q = f & 31;
        *(uint4*)&lmaskU[r * 132 + q * 4] = ((const uint4*)mrows)[(size_t)mids[r] * 32 + q];
    }
    for (int f = t; f < nm * 64; f += 256) {
        int i = f >> 6, c = f & 63;
        if (!tpm[b * SS + st * 64 + c])
            out[(size_t)mids[i] * SS + st * 64 + c] = NEG_INF;
    }
    __syncthreads();

    const int nact = snact;
    const int i2 = t & 15, sg = t >> 4;

    for (int g = 0; g * 32 < nact; ++g) {
        if (g) __syncthreads();
        const int nv = min(32, nact - g * 32);
        for (int f = t; f < nv * 32; f += 256) {
            int r = f >> 5, q = f & 31;
            size_t row = (size_t)b * SS + st * 64 + sact[g * 32 + r];
            *(uint4*)&srowU[r * 132 + q * 4] = ((const uint4*)p2)[row * 32 + q];
        }
        __syncthreads();

        float a00 = 0.f, a01 = 0.f, a10 = 0.f, a11 = 0.f;
        #pragma unroll 4
        for (int stp = 0; stp < 32; ++stp) {
            const uint4 A0 = *(const uint4*)&lmaskU[i2 * 132 + stp * 4];
            const uint4 A1 = *(const uint4*)&lmaskU[(i2 + 16) * 132 + stp * 4];
            const uint4 B0 = *(const uint4*)&srowU[sg * 132 + stp * 4];
            const uint4 B1 = *(const uint4*)&srowU[(sg + 16) * 132 + stp * 4];
            float a0[8], a1[8], b0[8], b1[8];
            a0[0] = bflo(A0.x); a0[1] = bfhi(A0.x); a0[2] = bflo(A0.y); a0[3] = bfhi(A0.y);
            a0[4] = bflo(A0.z); a0[5] = bfhi(A0.z); a0[6] = bflo(A0.w); a0[7] = bfhi(A0.w);
            a1[0] = bflo(A1.x); a1[1] = bfhi(A1.x); a1[2] = bflo(A1.y); a1[3] = bfhi(A1.y);
            a1[4] = bflo(A1.z); a1[5] = bfhi(A1.z); a1[6] = bflo(A1.w); a1[7] = bfhi(A1.w);
            b0[0] = bflo(B0.x); b0[1] = bfhi(B0.x); b0[2] = bflo(B0.y); b0[3] = bfhi(B0.y);
            b0[4] = bflo(B0.z); b0[5] = bfhi(B0.z); b0[6] = bflo(B0.w); b0[7] = bfhi(B0.w);
            b1[0] = bflo(B1.x); b1[1] = bfhi(B1.x); b1[2] = bflo(B1.y); b1[3] = bfhi(B1.y);
            b1[4] = bflo(B1.z); b1[5] = bfhi(B1.z); b1[6] = bflo(B1.w); b1[7] = bfhi(B1.w);
            #pragma unroll
            for (int jj = 0; jj < 8; ++jj) {
                a00 = fmaf(a0[jj], b0[jj], a00);
                a01 = fmaf(a0[jj], b1[jj], a01);
                a10 = fmaf(a1[jj], b0[jj], a10);
                a11 = fmaf(a1[jj], b1[jj], a11);
            }
        }

        const int iA = g * 32 + sg, iB = iA + 16;
        if (i2 < nm) {
            size_t ob = (size_t)mids[i2] * SS + st * 64;
            if (iA < nact) out[ob + sact[iA]] = a00;
            if (iB < nact) out[ob + sact[iB]] = a01;
        }
        if (i2 + 16 < nm) {
            size_t ob = (size_t)mids[i2 + 16] * SS + st * 64;
            if (iA < nact) out[ob + sact[iA]] = a10;
            if (iB < nact) out[ob + sact[iB]] = a11;
        }
    }
}

extern "C" void kernel_launch(void* const* d_in, const int* in_sizes, int n_in,
                              void* d_out, int out_size, void* d_ws, size_t ws_size,
                              hipStream_t stream) {
    const float* tok = (const float*)d_in[0];
    const float* w1  = (const float*)d_in[1];
    const float* b1  = (const float*)d_in[2];
    const float* w2  = (const float*)d_in[3];
    const float* b2  = (const float*)d_in[4];
    const int* edges = (const int*)d_in[5];
    const int* lmi   = (const int*)d_in[6];
    const int* bp    = (const int*)d_in[7];
    const int* tpm   = (const int*)d_in[8];

    float* out_lemmas = (float*)d_out;
    float* out_lm     = (float*)d_out + NEDGE;

    char* ws = (char*)d_ws;
    float* vc        = (float*)(ws + OFF_VC);
    int* msorted     = (int*)(ws + OFF_MSORT);
    int* bstart      = (int*)(ws + OFF_BSTART);
    unsigned* pslab  = (unsigned*)(ws + OFF_PSLAB);
    unsigned* qslab  = (unsigned*)(ws + OFF_QSLAB);
    unsigned* p2     = (unsigned*)(ws + OFF_P2);
    unsigned* mrows  = (unsigned*)(ws + OFF_MROWS);

    setup_k<<<2, 256, 0, stream>>>(w1, b1, w2, b2, bp, vc, msorted, bstart);
    compact<<<NROWS / 4 + MM / 4, 256, 0, stream>>>(tok, vc, lmi, pslab, qslab, p2, mrows);
    edge_fused<<<(NEDGE + 255) / 256, 256, 0, stream>>>(pslab, qslab, edges, vc, out_lemmas);
    lm_gemm<<<dim3(BB, 4, 8), 256, 0, stream>>>(p2, mrows, msorted, bstart, tpm, out_lm);
}

// Round 5
// 278.076 us; speedup vs baseline: 1.2679x; 1.0442x over previous
//
#include <hip/hip_runtime.h>

#define DD 256        // D
#define SS 256        // S
#define BB 64         // B
#define NEDGE 500000  // E
#define MM 2048       // M
#define NEG_INF -10000000000.0f
#define ROWF4 512     // float4 stride between consecutive (b,s) type rows in token_reprs
#define NROWS (BB * SS)  // 16384

// workspace byte offsets
#define OFF_VC     0
#define OFF_MSORT  4096
#define OFF_BSTART (4096 + MM * 4)
#define OFF_ASLAB  (1 << 16)
#define OFF_P2     ((1 << 16) + (8 << 20))
#define OFF_MROWS  ((1 << 16) + (16 << 20))

__device__ __forceinline__ float bflo(unsigned u) { return __uint_as_float(u << 16); }
__device__ __forceinline__ float bfhi(unsigned u) { return __uint_as_float(u & 0xFFFF0000u); }
__device__ __forceinline__ unsigned short bf_rne(float f) {
    unsigned u = __float_as_uint(f);
    return (unsigned short)((u + 0x7FFFu + ((u >> 16) & 1u)) >> 16);
}
__device__ __forceinline__ unsigned pack2_rne(float a, float b) {
    return (unsigned)bf_rne(a) | ((unsigned)bf_rne(b) << 16);
}

// block 0: vc[d] = sum_j w1[d,j]*w2[j], vc[256] = b1.w2+b2
// block 1: counting-sort m by batch pointer
__global__ void setup_k(const float* __restrict__ w1, const float* __restrict__ b1,
                        const float* __restrict__ w2, const float* __restrict__ b2,
                        const int* __restrict__ bp,
                        float* __restrict__ vc, int* __restrict__ msorted,
                        int* __restrict__ bstart) {
    const int t = threadIdx.x;
    if (blockIdx.x == 0) {
        float acc = 0.f;
        #pragma unroll 4
        for (int j = 0; j < DD / 2; ++j) acc += w1[t * (DD / 2) + j] * w2[j];
        vc[t] = acc;
        if (t == 0) {
            float c = b2[0];
            for (int j = 0; j < DD / 2; ++j) c += b1[j] * w2[j];
            vc[DD] = c;
        }
    } else {
        __shared__ int hist[BB];
        __shared__ int offs[BB + 1];
        if (t < BB) hist[t] = 0;
        __syncthreads();
        for (int m = t; m < MM; m += 256) atomicAdd(&hist[bp[m]], 1);
        __syncthreads();
        if (t == 0) {
            int acc = 0;
            for (int i = 0; i < BB; ++i) { offs[i] = acc; acc += hist[i]; }
            offs[BB] = acc;
        }
        __syncthreads();
        if (t < BB + 1) bstart[t] = offs[t];
        __syncthreads();
        for (int m = t; m < MM; m += 256) {
            int pos = atomicAdd(&offs[bp[m]], 1);
            msorted[pos] = m;
        }
    }
}

// Compact strided fp32 rows into dense bf16 tables:
//  blocks [0, NROWS/4): type rows -> aslab (slice-major, SINGLE shared table)
//                       + P2 (row-major, for lm staging)
//  blocks [NROWS/4, +MM/4): mask rows via lm_indices -> mrows (row-major)
__global__ __launch_bounds__(256) void compact(
        const float* __restrict__ tok, const int* __restrict__ lmi,
        unsigned* __restrict__ aslab,
        unsigned* __restrict__ p2, unsigned* __restrict__ mrows) {
    const int lane = threadIdx.x & 63;
    const int w    = threadIdx.x >> 6;
    if (blockIdx.x < NROWS / 4) {
        const int row = blockIdx.x * 4 + w;
        const float4 a = ((const float4*)tok)[(size_t)row * ROWF4 + lane];
        unsigned p0 = pack2_rne(a.x, a.y), p1 = pack2_rne(a.z, a.w);
        const int k = lane >> 3, sub = lane & 7;
        const size_t si = (size_t)(k * NROWS + row) * 16 + sub * 2;
        aslab[si] = p0; aslab[si + 1] = p1;
        const size_t pi = (size_t)row * 128 + lane * 2;
        p2[pi] = p0; p2[pi + 1] = p1;
    } else {
        const int m = (blockIdx.x - NROWS / 4) * 4 + w;
        const float4 a = ((const float4*)(tok + (size_t)lmi[m] * DD))[lane];
        mrows[(size_t)m * 128 + lane * 2]     = pack2_rne(a.x, a.y);
        mrows[(size_t)m * 128 + lane * 2 + 1] = pack2_rne(a.z, a.w);
    }
}

// Fused edge kernel: 256 edges/block, k-loop (8 slices of 32 dims) inside.
// SINGLE 2MB-per-k table serves both scope and goal gathers -> per-XCD-L2
// resident with headroom. v applied from per-lane registers (lane owns 4
// fixed dims per k).
__global__ __launch_bounds__(256) void edge_fused(
        const unsigned* __restrict__ aslab,
        const int* __restrict__ edges, const float* __restrict__ vc,
        float* __restrict__ out) {
    const int t = threadIdx.x;
    const int lane = t & 63, w = t >> 6;
    const int sub = lane & 7, j = lane >> 3;
    const int e0 = blockIdx.x * 256;
    __shared__ int sIdx[2][256];
    __shared__ float accs[256];
    const int e = e0 + t;
    const bool val = e < NEDGE;
    sIdx[0][t] = val ? __builtin_nontemporal_load(edges + e) : 0;
    sIdx[1][t] = val ? __builtin_nontemporal_load(edges + NEDGE + e) : 0;

    // per-lane v: dims k*32 + sub*4 .. +4 for each k
    float4 v4[8];
    #pragma unroll
    for (int k = 0; k < 8; ++k) v4[k] = ((const float4*)vc)[k * 8 + sub];
    __syncthreads();

    float acc[8];
    #pragma unroll
    for (int i = 0; i < 8; ++i) acc[i] = 0.f;
    const int slotbase = w * 64 + j;  // + i*8

    #pragma unroll 1
    for (int k = 0; k < 8; ++k) {
        const unsigned* base = aslab + (size_t)k * NROWS * 16 + sub * 2;
        const float4 v = v4[k];
        #pragma unroll
        for (int i = 0; i < 8; ++i) {
            const int slot = slotbase + i * 8;
            const int sc = sIdx[0][slot];
            const int gl = sIdx[1][slot];
            const uint2 pu = *(const uint2*)(base + (size_t)sc * 16);
            const uint2 qu = *(const uint2*)(base + (size_t)gl * 16);
            acc[i] += (bflo(pu.x) * bflo(qu.x)) * v.x
                    + (bfhi(pu.x) * bfhi(qu.x)) * v.y
                    + (bflo(pu.y) * bflo(qu.y)) * v.z
                    + (bfhi(pu.y) * bfhi(qu.y)) * v.w;
        }
    }
    #pragma unroll
    for (int i = 0; i < 8; ++i) {
        float p = acc[i];
        p += __shfl_down(p, 4, 8);
        p += __shfl_down(p, 2, 8);
        p += __shfl_down(p, 1, 8);
        if (sub == 0) accs[slotbase + i * 8] = p;
    }
    __syncthreads();
    if (val) __builtin_nontemporal_store(accs[t] + vc[DD], out + e);
}

// Per-batch grouped lm GEMM with masked-column skip; A and B staged from
// dense bf16 tables.
__global__ __launch_bounds__(256) void lm_gemm(
        const unsigned* __restrict__ p2,
        const unsigned* __restrict__ mrows,
        const int* __restrict__ msorted,
        const int* __restrict__ bstart,
        const int* __restrict__ tpm,
        float* __restrict__ out) {
    const int b  = blockIdx.x;
    const int st = blockIdx.y;   // 64-wide s tile
    const int ch = blockIdx.z;   // mask chunk
    const int s0 = bstart[b], s1 = bstart[b + 1];
    const int base = s0 + ch * 32;
    if (base >= s1) return;
    const int nm = min(32, s1 - base);
    const int t = threadIdx.x;

    __shared__ unsigned lmaskU[32 * 132];
    __shared__ unsigned srowU[32 * 132];
    __shared__ int mids[32];
    __shared__ int sact[64];
    __shared__ int snact;

    if (t < 32) mids[t] = msorted[base + min(t, nm - 1)];
    if (t >= 64 && t < 128) {  // wave 1: ballot-compact active columns
        int lt = t - 64;
        bool act = tpm[b * SS + st * 64 + lt] != 0;
        unsigned long long mk = __ballot(act);
        if (act) sact[__popcll(mk & ((1ull << lt) - 1))] = lt;
        if (lt == 0) snact = (int)__popcll(mk);
    }
    __syncthreads();

    for (int f = t; f < nm * 32; f += 256) {
        int r = f >> 5, q = f & 31;
        *(uint4*)&lmaskU[r * 132 + q * 4] = ((const uint4*)mrows)[(size_t)mids[r] * 32 + q];
    }
    for (int f = t; f < nm * 64; f += 256) {
        int i = f >> 6, c = f & 63;
        if (!tpm[b * SS + st * 64 + c])
            out[(size_t)mids[i] * SS + st * 64 + c] = NEG_INF;
    }
    __syncthreads();

    const int nact = snact;
    const int i2 = t & 15, sg = t >> 4;

    for (int g = 0; g * 32 < nact; ++g) {
        if (g) __syncthreads();
        const int nv = min(32, nact - g * 32);
        for (int f = t; f < nv * 32; f += 256) {
            int r = f >> 5, q = f & 31;
            size_t row = (size_t)b * SS + st * 64 + sact[g * 32 + r];
            *(uint4*)&srowU[r * 132 + q * 4] = ((const uint4*)p2)[row * 32 + q];
        }
        __syncthreads();

        float a00 = 0.f, a01 = 0.f, a10 = 0.f, a11 = 0.f;
        #pragma unroll 4
        for (int stp = 0; stp < 32; ++stp) {
            const uint4 A0 = *(const uint4*)&lmaskU[i2 * 132 + stp * 4];
            const uint4 A1 = *(const uint4*)&lmaskU[(i2 + 16) * 132 + stp * 4];
            const uint4 B0 = *(const uint4*)&srowU[sg * 132 + stp * 4];
            const uint4 B1 = *(const uint4*)&srowU[(sg + 16) * 132 + stp * 4];
            float a0[8], a1[8], b0[8], b1[8];
            a0[0] = bflo(A0.x); a0[1] = bfhi(A0.x); a0[2] = bflo(A0.y); a0[3] = bfhi(A0.y);
            a0[4] = bflo(A0.z); a0[5] = bfhi(A0.z); a0[6] = bflo(A0.w); a0[7] = bfhi(A0.w);
            a1[0] = bflo(A1.x); a1[1] = bfhi(A1.x); a1[2] = bflo(A1.y); a1[3] = bfhi(A1.y);
            a1[4] = bflo(A1.z); a1[5] = bfhi(A1.z); a1[6] = bflo(A1.w); a1[7] = bfhi(A1.w);
            b0[0] = bflo(B0.x); b0[1] = bfhi(B0.x); b0[2] = bflo(B0.y); b0[3] = bfhi(B0.y);
            b0[4] = bflo(B0.z); b0[5] = bfhi(B0.z); b0[6] = bflo(B0.w); b0[7] = bfhi(B0.w);
            b1[0] = bflo(B1.x); b1[1] = bfhi(B1.x); b1[2] = bflo(B1.y); b1[3] = bfhi(B1.y);
            b1[4] = bflo(B1.z); b1[5] = bfhi(B1.z); b1[6] = bflo(B1.w); b1[7] = bfhi(B1.w);
            #pragma unroll
            for (int jj = 0; jj < 8; ++jj) {
                a00 = fmaf(a0[jj], b0[jj], a00);
                a01 = fmaf(a0[jj], b1[jj], a01);
                a10 = fmaf(a1[jj], b0[jj], a10);
                a11 = fmaf(a1[jj], b1[jj], a11);
            }
        }

        const int iA = g * 32 + sg, iB = iA + 16;
        if (i2 < nm) {
            size_t ob = (size_t)mids[i2] * SS + st * 64;
            if (iA < nact) out[ob + sact[iA]] = a00;
            if (iB < nact) out[ob + sact[iB]] = a01;
        }
        if (i2 + 16 < nm) {
            size_t ob = (size_t)mids[i2 + 16] * SS + st * 64;
            if (iA < nact) out[ob + sact[iA]] = a10;
            if (iB < nact) out[ob + sact[iB]] = a11;
        }
    }
}

extern "C" void kernel_launch(void* const* d_in, const int* in_sizes, int n_in,
                              void* d_out, int out_size, void* d_ws, size_t ws_size,
                              hipStream_t stream) {
    const float* tok = (const float*)d_in[0];
    const float* w1  = (const float*)d_in[1];
    const float* b1  = (const float*)d_in[2];
    const float* w2  = (const float*)d_in[3];
    const float* b2  = (const float*)d_in[4];
    const int* edges = (const int*)d_in[5];
    const int* lmi   = (const int*)d_in[6];
    const int* bp    = (const int*)d_in[7];
    const int* tpm   = (const int*)d_in[8];

    float* out_lemmas = (float*)d_out;
    float* out_lm     = (float*)d_out + NEDGE;

    char* ws = (char*)d_ws;
    float* vc        = (float*)(ws + OFF_VC);
    int* msorted     = (int*)(ws + OFF_MSORT);
    int* bstart      = (int*)(ws + OFF_BSTART);
    unsigned* aslab  = (unsigned*)(ws + OFF_ASLAB);
    unsigned* p2     = (unsigned*)(ws + OFF_P2);
    unsigned* mrows  = (unsigned*)(ws + OFF_MROWS);

    setup_k<<<2, 256, 0, stream>>>(w1, b1, w2, b2, bp, vc, msorted, bstart);
    compact<<<NROWS / 4 + MM / 4, 256, 0, stream>>>(tok, lmi, aslab, p2, mrows);
    edge_fused<<<(NEDGE + 255) / 256, 256, 0, stream>>>(aslab, edges, vc, out_lemmas);
    lm_gemm<<<dim3(BB, 4, 8), 256, 0, stream>>>(p2, mrows, msorted, bstart, tpm, out_lm);
}